// Round 4
// baseline (49.391 us; speedup 1.0000x reference)
//
#include <hip/hip_runtime.h>

// Top1Gate via bf16x3-split MFMA GEMM, v4.
// logits = x @ W^T [16384,64]; idx = argmax; scores = max; mask = one-hot.
// Output flat (float32): [idx 16384][scores 16384][mask 16384*64]
//
// v4 vs v3: B issued BEFORE x each iter (vmcnt retires in order — waiting for
// L2-B no longer drains the newest HBM-x chunk); x prefetch 3 ahead (4-deep
// LDS ring); exact peeled-tail vmcnt counts. One barrier per chunk.

typedef float  f32x4  __attribute__((ext_vector_type(4)));
typedef short  bf16x8 __attribute__((ext_vector_type(8)));

constexpr int BATCH = 16384;
constexpr int DM    = 2048;
constexpr int NE    = 64;
constexpr int BM    = 32;          // rows per block
constexpr int KB    = 64;          // K per staged chunk
constexpr int NT    = 256;         // 4 waves: 2 row-tiles x 2 k-halves
constexpr int NCH   = DM / KB;     // 32 chunks

// wf layout (d_ws, ushort): [ks=64][term=2][tile=4][lane=64][j=8]
// value = w_term[expert = tile*16 + (lane&15)][k = ks*32 + (lane>>4)*8 + j]

__device__ __forceinline__ void split_bf16(float f, unsigned short& hi, unsigned short& lo) {
    unsigned u  = __float_as_uint(f);
    unsigned h  = (u + 0x8000u) >> 16;           // round-half-up to bf16
    float    hf = __uint_as_float(h << 16);
    unsigned l  = __float_as_uint(f - hf) >> 16; // truncate residual
    hi = (unsigned short)h;
    lo = (unsigned short)l;
}

__global__ __launch_bounds__(256, 1)
void wconv_kernel(const float* __restrict__ w, unsigned short* __restrict__ wf) {
    int i  = blockIdx.x * 256 + threadIdx.x;     // 0..131071
    int ks = i >> 11;
    int n  = (i >> 9) & 3;
    int l  = (i >> 3) & 63;
    int j  = i & 7;
    int e  = n * 16 + (l & 15);
    int k  = ks * 32 + (l >> 4) * 8 + j;
    float v = w[(size_t)e * DM + k];
    unsigned short hi, lo;
    split_bf16(v, hi, lo);
    int base = ((ks * 2 + 0) * 4 + n) * 512 + l * 8 + j;
    wf[base]        = hi;               // term 0
    wf[base + 2048] = lo;               // term 1
}

struct BSet { bf16x8 v[8]; };   // [term=2][tile=4]

__global__ __launch_bounds__(NT, 2)
void gate_kernel(const float* __restrict__ x,
                 const unsigned short* __restrict__ wf,
                 float* __restrict__ out) {
    __shared__ alignas(16) float xs[4][BM * KB];   // 4 x 8 KB ring, swizzled f4 slots
    __shared__ float lg[BM][NE + 1];               // stride 65: conflict-free scan
    __shared__ int   s_idx[BM];

    const int t    = threadIdx.x;
    const int lane = t & 63;
    const int wv   = t >> 6;
    const int rt   = wv >> 1;      // row-tile 0/1
    const int kh   = wv & 1;       // k-half 0/1
    const int row0 = blockIdx.x * BM;

    f32x4 acc[4];
    #pragma unroll
    for (int n = 0; n < 4; ++n) acc[n] = (f32x4){0.f, 0.f, 0.f, 0.f};

    // stage x chunk c into ring buffer b: 32 rows x 64 k fp32 = 512 f4, 2/thread
    auto stage_x = [&](int c, int b) {
        const float* xg = x + (size_t)row0 * DM + c * KB;
        #pragma unroll
        for (int i = 0; i < 2; ++i) {
            int d    = i * NT + t;       // 0..511 linear dest f4 slot
            int r    = d >> 4;
            int sdst = d & 15;
            int ssrc = sdst ^ (r & 7);   // pre-swizzled source (linear LDS dest)
            __builtin_amdgcn_global_load_lds(
                (const __attribute__((address_space(1))) void*)(xg + (size_t)r * DM + ssrc * 4),
                (__attribute__((address_space(3))) void*)(&xs[b][d * 4]),
                16, 0, 0);
        }
    };

    // load this wave's B fragments for chunk c (k-step = kh) into registers (L2-hot)
    auto load_b = [&](int c, BSet& B) {
        int ks = c * 2 + kh;
        const unsigned short* wg = wf + (size_t)(ks * 8) * 512 + lane * 8;
        #pragma unroll
        for (int f = 0; f < 8; ++f)           // f = term*4 + tile
            B.v[f] = *(const bf16x8*)(wg + (size_t)f * 512);
    };

    auto compute = [&](int b, const BSet& B) {
        const int rA  = rt * 16 + (lane & 15);
        const int fs0 = kh * 8 + (lane >> 4) * 2;
        f32x4 a0 = *(const f32x4*)&xs[b][(rA * 16 + ((fs0 + 0) ^ (rA & 7))) * 4];
        f32x4 a1 = *(const f32x4*)&xs[b][(rA * 16 + ((fs0 + 1) ^ (rA & 7))) * 4];
        bf16x8 ahi, alo;
        #pragma unroll
        for (int j = 0; j < 8; ++j) {
            float f = (j < 4) ? a0[j] : a1[j - 4];
            unsigned short h, l;
            split_bf16(f, h, l);
            ahi[j] = (short)h;
            alo[j] = (short)l;
        }
        #pragma unroll
        for (int n = 0; n < 4; ++n) {
            acc[n] = __builtin_amdgcn_mfma_f32_16x16x32_bf16(ahi, B.v[0 + n], acc[n], 0, 0, 0);
            acc[n] = __builtin_amdgcn_mfma_f32_16x16x32_bf16(ahi, B.v[4 + n], acc[n], 0, 0, 0);
            acc[n] = __builtin_amdgcn_mfma_f32_16x16x32_bf16(alo, B.v[0 + n], acc[n], 0, 0, 0);
        }
    };

    BSet BA, BB;

    // prologue: X(0),X(1) staged; B(0); X(2). queue=[X0:2,X1:2,B0:8,X2:2]=14
    stage_x(0, 0);
    stage_x(1, 1);
    load_b(0, BA);
    stage_x(2, 2);
    asm volatile("s_waitcnt vmcnt(12)" ::: "memory");   // X(0) landed
    __builtin_amdgcn_sched_barrier(0);
    __builtin_amdgcn_s_barrier();

    // steady state: iter c issues [B(c+1), X(c+3)], waits vmcnt(12):
    // queue=[X(c+1):2, B(c):8, X(c+2):2, B(c+1):8, X(c+3):2]=22 -> drain thru B(c),
    // leaving 2 x-chunks + B(c+1) in flight. compute(c), barrier.
    #pragma unroll 1
    for (int c = 0; c < 28; c += 2) {
        // iter c (even): BA current, load B(c+1) -> BB
        load_b(c + 1, BB);
        stage_x(c + 3, (c + 3) & 3);
        asm volatile("s_waitcnt vmcnt(12)" ::: "memory");
        __builtin_amdgcn_sched_barrier(0);
        compute(c & 3, BA);
        __builtin_amdgcn_s_barrier();
        // iter c+1 (odd): BB current, load B(c+2) -> BA
        load_b(c + 2, BA);
        stage_x(c + 4, (c + 4) & 3);
        asm volatile("s_waitcnt vmcnt(12)" ::: "memory");
        __builtin_amdgcn_sched_barrier(0);
        compute((c + 1) & 3, BB);
        __builtin_amdgcn_s_barrier();
    }
    // c=28 (even, BA): issues B(29)->BB, X(31). queue=[X29:2,B28:8,X30:2,B29:8,X31:2]=22
    load_b(29, BB);
    stage_x(31, 31 & 3);
    asm volatile("s_waitcnt vmcnt(12)" ::: "memory");
    __builtin_amdgcn_sched_barrier(0);
    compute(28 & 3, BA);
    __builtin_amdgcn_s_barrier();
    // c=29 (BB): issues B(30)->BA. queue=[X30:2,B29:8,X31:2,B30:8]=20 -> drain thru B29
    load_b(30, BA);
    asm volatile("s_waitcnt vmcnt(10)" ::: "memory");
    __builtin_amdgcn_sched_barrier(0);
    compute(29 & 3, BB);
    __builtin_amdgcn_s_barrier();
    // c=30 (BA): issues B(31)->BB. queue=[X31:2,B30:8,B31:8]=18 -> drain thru B30
    load_b(31, BB);
    asm volatile("s_waitcnt vmcnt(8)" ::: "memory");
    __builtin_amdgcn_sched_barrier(0);
    compute(30 & 3, BA);
    __builtin_amdgcn_s_barrier();
    // c=31 (BB): drain all
    asm volatile("s_waitcnt vmcnt(0)" ::: "memory");
    __builtin_amdgcn_sched_barrier(0);
    compute(31 & 3, BB);
    __syncthreads();

    // k-reduce across wave pairs + logits to LDS
    // C/D layout: row_local = (lane>>4)*4+q, col = n*16 + (lane&15)
    const int rloc = rt * 16 + ((lane >> 4) << 2);
    const int cb   = lane & 15;
    if (kh == 1) {
        #pragma unroll
        for (int n = 0; n < 4; ++n)
            #pragma unroll
            for (int q = 0; q < 4; ++q)
                lg[rloc + q][n * 16 + cb] = acc[n][q];
    }
    __syncthreads();
    if (kh == 0) {
        #pragma unroll
        for (int n = 0; n < 4; ++n)
            #pragma unroll
            for (int q = 0; q < 4; ++q)
                lg[rloc + q][n * 16 + cb] += acc[n][q];
    }
    __syncthreads();

    if (t < BM) {
        float m  = lg[t][0];
        int   mi = 0;
        #pragma unroll
        for (int e = 1; e < NE; ++e) {
            float v = lg[t][e];
            if (v > m) { m = v; mi = e; }
        }
        s_idx[t] = mi;
        out[row0 + t]         = (float)mi;
        out[BATCH + row0 + t] = m;
    }
    __syncthreads();

    // one-hot mask: 32 rows x 64 = 2048 floats; 8/thread, coalesced f32x4
    float* mask = out + 2 * (size_t)BATCH;
    int r  = t >> 3;
    int c0 = (t & 7) * 8;
    int mi = s_idx[r];
    #pragma unroll
    for (int i = 0; i < 2; ++i) {
        f32x4 v;
        #pragma unroll
        for (int j = 0; j < 4; ++j) v[j] = (c0 + i * 4 + j == mi) ? 1.0f : 0.0f;
        *(f32x4*)&mask[(size_t)(row0 + r) * NE + c0 + i * 4] = v;
    }
}

extern "C" void kernel_launch(void* const* d_in, const int* in_sizes, int n_in,
                              void* d_out, int out_size, void* d_ws, size_t ws_size,
                              hipStream_t stream) {
    const float* x = (const float*)d_in[0];
    const float* w = (const float*)d_in[1];
    float* out     = (float*)d_out;
    unsigned short* wf = (unsigned short*)d_ws;   // 512 KB

    wconv_kernel<<<dim3(512), dim3(256), 0, stream>>>(w, wf);
    gate_kernel<<<dim3(BATCH / BM), dim3(NT), 0, stream>>>(x, wf, out);
}

// Round 5
// 39.783 us; speedup vs baseline: 1.2415x; 1.2415x over previous
//
#include <hip/hip_runtime.h>

// Top1Gate via bf16x3-split MFMA GEMM, v5.
// logits = x @ W^T [16384,64]; idx = argmax; scores = max; mask = one-hot.
// Output flat (float32): [idx 16384][scores 16384][mask 16384*64]
//
// v5 vs v4: per-block k-chunk DE-PHASING (CH(c) = (c + blockIdx&31) & 31).
// All blocks marching on the same 256B column slab at 8KB stride = HBM
// channel convoy -> ~50% BW. Rotating each block's chunk order spreads the
// instantaneous footprint across all channels. Everything else unchanged.

typedef float  f32x4  __attribute__((ext_vector_type(4)));
typedef short  bf16x8 __attribute__((ext_vector_type(8)));

constexpr int BATCH = 16384;
constexpr int DM    = 2048;
constexpr int NE    = 64;
constexpr int BM    = 32;          // rows per block
constexpr int KB    = 64;          // K per staged chunk
constexpr int NT    = 256;         // 4 waves: 2 row-tiles x 2 k-halves
constexpr int NCH   = DM / KB;     // 32 chunks

// wf layout (d_ws, ushort): [ks=64][term=2][tile=4][lane=64][j=8]
// value = w_term[expert = tile*16 + (lane&15)][k = ks*32 + (lane>>4)*8 + j]

__device__ __forceinline__ void split_bf16(float f, unsigned short& hi, unsigned short& lo) {
    unsigned u  = __float_as_uint(f);
    unsigned h  = (u + 0x8000u) >> 16;           // round-half-up to bf16
    float    hf = __uint_as_float(h << 16);
    unsigned l  = __float_as_uint(f - hf) >> 16; // truncate residual
    hi = (unsigned short)h;
    lo = (unsigned short)l;
}

__global__ __launch_bounds__(256, 1)
void wconv_kernel(const float* __restrict__ w, unsigned short* __restrict__ wf) {
    int i  = blockIdx.x * 256 + threadIdx.x;     // 0..131071
    int ks = i >> 11;
    int n  = (i >> 9) & 3;
    int l  = (i >> 3) & 63;
    int j  = i & 7;
    int e  = n * 16 + (l & 15);
    int k  = ks * 32 + (l >> 4) * 8 + j;
    float v = w[(size_t)e * DM + k];
    unsigned short hi, lo;
    split_bf16(v, hi, lo);
    int base = ((ks * 2 + 0) * 4 + n) * 512 + l * 8 + j;
    wf[base]        = hi;               // term 0
    wf[base + 2048] = lo;               // term 1
}

struct BSet { bf16x8 v[8]; };   // [term=2][tile=4]

__global__ __launch_bounds__(NT, 2)
void gate_kernel(const float* __restrict__ x,
                 const unsigned short* __restrict__ wf,
                 float* __restrict__ out) {
    __shared__ alignas(16) float xs[4][BM * KB];   // 4 x 8 KB ring, swizzled f4 slots
    __shared__ float lg[BM][NE + 1];               // stride 65: conflict-free scan
    __shared__ int   s_idx[BM];

    const int t     = threadIdx.x;
    const int lane  = t & 63;
    const int wv    = t >> 6;
    const int rt    = wv >> 1;      // row-tile 0/1
    const int kh    = wv & 1;       // k-half 0/1
    const int row0  = blockIdx.x * BM;
    const int phase = blockIdx.x & 31;   // de-phase chunk order across blocks

    f32x4 acc[4];
    #pragma unroll
    for (int n = 0; n < 4; ++n) acc[n] = (f32x4){0.f, 0.f, 0.f, 0.f};

    // stage x global-chunk gc into ring buffer b: 32 rows x 64 k = 512 f4, 2/thread
    auto stage_x = [&](int gc, int b) {
        const float* xg = x + (size_t)row0 * DM + gc * KB;
        #pragma unroll
        for (int i = 0; i < 2; ++i) {
            int d    = i * NT + t;       // 0..511 linear dest f4 slot
            int r    = d >> 4;
            int sdst = d & 15;
            int ssrc = sdst ^ (r & 7);   // pre-swizzled source (linear LDS dest)
            __builtin_amdgcn_global_load_lds(
                (const __attribute__((address_space(1))) void*)(xg + (size_t)r * DM + ssrc * 4),
                (__attribute__((address_space(3))) void*)(&xs[b][d * 4]),
                16, 0, 0);
        }
    };

    // load this wave's B fragments for global-chunk gc (k-step = kh), L2-hot
    auto load_b = [&](int gc, BSet& B) {
        int ks = gc * 2 + kh;
        const unsigned short* wg = wf + (size_t)(ks * 8) * 512 + lane * 8;
        #pragma unroll
        for (int f = 0; f < 8; ++f)           // f = term*4 + tile
            B.v[f] = *(const bf16x8*)(wg + (size_t)f * 512);
    };

    auto compute = [&](int b, const BSet& B) {
        const int rA  = rt * 16 + (lane & 15);
        const int fs0 = kh * 8 + (lane >> 4) * 2;
        f32x4 a0 = *(const f32x4*)&xs[b][(rA * 16 + ((fs0 + 0) ^ (rA & 7))) * 4];
        f32x4 a1 = *(const f32x4*)&xs[b][(rA * 16 + ((fs0 + 1) ^ (rA & 7))) * 4];
        bf16x8 ahi, alo;
        #pragma unroll
        for (int j = 0; j < 8; ++j) {
            float f = (j < 4) ? a0[j] : a1[j - 4];
            unsigned short h, l;
            split_bf16(f, h, l);
            ahi[j] = (short)h;
            alo[j] = (short)l;
        }
        #pragma unroll
        for (int n = 0; n < 4; ++n) {
            acc[n] = __builtin_amdgcn_mfma_f32_16x16x32_bf16(ahi, B.v[0 + n], acc[n], 0, 0, 0);
            acc[n] = __builtin_amdgcn_mfma_f32_16x16x32_bf16(ahi, B.v[4 + n], acc[n], 0, 0, 0);
            acc[n] = __builtin_amdgcn_mfma_f32_16x16x32_bf16(alo, B.v[0 + n], acc[n], 0, 0, 0);
        }
    };

    auto CH = [&](int c) { return (c + phase) & 31; };

    BSet BA, BB;

    // prologue: X(0),X(1) staged; B(0); X(2). queue=[X0:2,X1:2,B0:8,X2:2]=14
    stage_x(CH(0), 0);
    stage_x(CH(1), 1);
    load_b(CH(0), BA);
    stage_x(CH(2), 2);
    asm volatile("s_waitcnt vmcnt(12)" ::: "memory");   // X(0) landed
    __builtin_amdgcn_sched_barrier(0);
    __builtin_amdgcn_s_barrier();

    // steady state: iter c issues [B(c+1), X(c+3)], waits vmcnt(12):
    // queue=[X(c+1):2, B(c):8, X(c+2):2, B(c+1):8, X(c+3):2]=22 -> drain thru B(c),
    // leaving 2 x-chunks + B(c+1) in flight. compute(c), barrier.
    #pragma unroll 1
    for (int c = 0; c < 28; c += 2) {
        // iter c (even): BA current, load B(c+1) -> BB
        load_b(CH(c + 1), BB);
        stage_x(CH(c + 3), (c + 3) & 3);
        asm volatile("s_waitcnt vmcnt(12)" ::: "memory");
        __builtin_amdgcn_sched_barrier(0);
        compute(c & 3, BA);
        __builtin_amdgcn_s_barrier();
        // iter c+1 (odd): BB current, load B(c+2) -> BA
        load_b(CH(c + 2), BA);
        stage_x(CH(c + 4), (c + 4) & 3);
        asm volatile("s_waitcnt vmcnt(12)" ::: "memory");
        __builtin_amdgcn_sched_barrier(0);
        compute((c + 1) & 3, BB);
        __builtin_amdgcn_s_barrier();
    }
    // c=28 (even, BA): issues B(29)->BB, X(31). queue=[X29:2,B28:8,X30:2,B29:8,X31:2]=22
    load_b(CH(29), BB);
    stage_x(CH(31), 31 & 3);
    asm volatile("s_waitcnt vmcnt(12)" ::: "memory");
    __builtin_amdgcn_sched_barrier(0);
    compute(28 & 3, BA);
    __builtin_amdgcn_s_barrier();
    // c=29 (BB): issues B(30)->BA. queue=[X30:2,B29:8,X31:2,B30:8]=20 -> drain thru B29
    load_b(CH(30), BA);
    asm volatile("s_waitcnt vmcnt(10)" ::: "memory");
    __builtin_amdgcn_sched_barrier(0);
    compute(29 & 3, BB);
    __builtin_amdgcn_s_barrier();
    // c=30 (BA): issues B(31)->BB. queue=[X31:2,B30:8,B31:8]=18 -> drain thru B30
    load_b(CH(31), BB);
    asm volatile("s_waitcnt vmcnt(8)" ::: "memory");
    __builtin_amdgcn_sched_barrier(0);
    compute(30 & 3, BA);
    __builtin_amdgcn_s_barrier();
    // c=31 (BB): drain all
    asm volatile("s_waitcnt vmcnt(0)" ::: "memory");
    __builtin_amdgcn_sched_barrier(0);
    compute(31 & 3, BB);
    __syncthreads();

    // k-reduce across wave pairs + logits to LDS
    // C/D layout: row_local = (lane>>4)*4+q, col = n*16 + (lane&15)
    const int rloc = rt * 16 + ((lane >> 4) << 2);
    const int cb   = lane & 15;
    if (kh == 1) {
        #pragma unroll
        for (int n = 0; n < 4; ++n)
            #pragma unroll
            for (int q = 0; q < 4; ++q)
                lg[rloc + q][n * 16 + cb] = acc[n][q];
    }
    __syncthreads();
    if (kh == 0) {
        #pragma unroll
        for (int n = 0; n < 4; ++n)
            #pragma unroll
            for (int q = 0; q < 4; ++q)
                lg[rloc + q][n * 16 + cb] += acc[n][q];
    }
    __syncthreads();

    if (t < BM) {
        float m  = lg[t][0];
        int   mi = 0;
        #pragma unroll
        for (int e = 1; e < NE; ++e) {
            float v = lg[t][e];
            if (v > m) { m = v; mi = e; }
        }
        s_idx[t] = mi;
        out[row0 + t]         = (float)mi;
        out[BATCH + row0 + t] = m;
    }
    __syncthreads();

    // one-hot mask: 32 rows x 64 = 2048 floats; 8/thread, coalesced f32x4
    float* mask = out + 2 * (size_t)BATCH;
    int r  = t >> 3;
    int c0 = (t & 7) * 8;
    int mi = s_idx[r];
    #pragma unroll
    for (int i = 0; i < 2; ++i) {
        f32x4 v;
        #pragma unroll
        for (int j = 0; j < 4; ++j) v[j] = (c0 + i * 4 + j == mi) ? 1.0f : 0.0f;
        *(f32x4*)&mask[(size_t)(row0 + r) * NE + c0 + i * 4] = v;
    }
}

extern "C" void kernel_launch(void* const* d_in, const int* in_sizes, int n_in,
                              void* d_out, int out_size, void* d_ws, size_t ws_size,
                              hipStream_t stream) {
    const float* x = (const float*)d_in[0];
    const float* w = (const float*)d_in[1];
    float* out     = (float*)d_out;
    unsigned short* wf = (unsigned short*)d_ws;   // 512 KB

    wconv_kernel<<<dim3(512), dim3(256), 0, stream>>>(w, wf);
    gate_kernel<<<dim3(BATCH / BM), dim3(NT), 0, stream>>>(x, wf, out);
}

// Round 6
// 37.106 us; speedup vs baseline: 1.3311x; 1.0721x over previous
//
#include <hip/hip_runtime.h>

// Top1Gate via bf16x3-split MFMA GEMM, v6.
// logits = x @ W^T [16384,64]; idx = argmax; scores = max; mask = one-hot.
// Output flat (float32): [idx 16384][scores 16384][mask 16384*64]
//
// v6 vs v5: chunk geometry 32x64 -> 16x128 (512B HBM runs: 2x intra-block
// channel spread); waves = 4 k-quarters (all active every chunk); B-sets
// loaded once per kblk, reused across the (h=0,h=1) chunk pair (B L2 traffic
// halved, zero redundancy). Even de-phasing preserves kblk pairing.

typedef float  f32x4  __attribute__((ext_vector_type(4)));
typedef short  bf16x8 __attribute__((ext_vector_type(8)));

constexpr int BATCH = 16384;
constexpr int DM    = 2048;
constexpr int NE    = 64;
constexpr int BM    = 32;          // rows per block
constexpr int NT    = 256;         // 4 waves = 4 k-quarters
// chunk = 16 rows x 128 k = 8 KB; 32 chunks: c -> (h = c&1 row-half, kblk = 0..15)

// wf layout (d_ws, ushort): [ks=64][term=2][tile=4][lane=64][j=8]
// value = w_term[expert = tile*16 + (lane&15)][k = ks*32 + (lane>>4)*8 + j]

__device__ __forceinline__ void split_bf16(float f, unsigned short& hi, unsigned short& lo) {
    unsigned u  = __float_as_uint(f);
    unsigned h  = (u + 0x8000u) >> 16;           // round-half-up to bf16
    float    hf = __uint_as_float(h << 16);
    unsigned l  = __float_as_uint(f - hf) >> 16; // truncate residual
    hi = (unsigned short)h;
    lo = (unsigned short)l;
}

__global__ __launch_bounds__(256, 1)
void wconv_kernel(const float* __restrict__ w, unsigned short* __restrict__ wf) {
    int i  = blockIdx.x * 256 + threadIdx.x;     // 0..131071
    int ks = i >> 11;
    int n  = (i >> 9) & 3;
    int l  = (i >> 3) & 63;
    int j  = i & 7;
    int e  = n * 16 + (l & 15);
    int k  = ks * 32 + (l >> 4) * 8 + j;
    float v = w[(size_t)e * DM + k];
    unsigned short hi, lo;
    split_bf16(v, hi, lo);
    int base = ((ks * 2 + 0) * 4 + n) * 512 + l * 8 + j;
    wf[base]        = hi;               // term 0
    wf[base + 2048] = lo;               // term 1
}

struct BSet { bf16x8 v[8]; };   // [term=2][tile=4] for one 32-k step

__global__ __launch_bounds__(NT, 2)
void gate_kernel(const float* __restrict__ x,
                 const unsigned short* __restrict__ wf,
                 float* __restrict__ out) {
    __shared__ alignas(16) float xs[4][16 * 32 * 4];   // 4-slot ring x 8 KB (16 rows x 32 f4)
    __shared__ float lg[BM][NE + 1];                   // stride 65: conflict-free
    __shared__ int   s_idx[BM];

    const int t     = threadIdx.x;
    const int lane  = t & 63;
    const int q     = t >> 6;                 // k-quarter 0..3
    const int row0  = blockIdx.x * BM;
    const int phase = (blockIdx.x & 15) << 1; // EVEN de-phase: preserves kblk pairing

    f32x4 acc[2][4];
    #pragma unroll
    for (int h = 0; h < 2; ++h)
        #pragma unroll
        for (int n = 0; n < 4; ++n) acc[h][n] = (f32x4){0.f, 0.f, 0.f, 0.f};

    auto kbOf = [&](int c) { return ((c + phase) >> 1) & 15; };

    // stage logical chunk c into ring slot b: 16 rows x 128 k = 512 f4, 2/thread
    auto stage_x = [&](int c, int b) {
        const int h = c & 1;
        const float* xg = x + (size_t)(row0 + h * 16) * DM + kbOf(c) * 128;
        #pragma unroll
        for (int i = 0; i < 2; ++i) {
            int d    = i * NT + t;            // 0..511 linear dest f4 slot
            int r    = d >> 5;                // row 0..15
            int sdst = d & 31;                // slot within row
            int ssrc = sdst ^ ((r & 7) << 2); // pre-swizzled source (linear LDS dest)
            __builtin_amdgcn_global_load_lds(
                (const __attribute__((address_space(1))) void*)(xg + (size_t)r * DM + ssrc * 4),
                (__attribute__((address_space(3))) void*)(&xs[b][d * 4]),
                16, 0, 0);
        }
    };

    // load this wave's B fragments for logical chunk c's kblk (k-step = quarter q)
    auto load_b = [&](int c, BSet& B) {
        int ks = kbOf(c) * 4 + q;
        const unsigned short* wg = wf + (size_t)ks * 4096 + lane * 8;
        #pragma unroll
        for (int f = 0; f < 8; ++f)           // f = term*4 + tile
            B.v[f] = *(const bf16x8*)(wg + (size_t)f * 512);
    };

    // compute chunk in slot b (row-half hh literal), this wave's 32-k quarter
    auto compute = [&](int b, int hh, const BSet& B) {
        const int rA = lane & 15;                       // row within chunk
        const int s0 = q * 8 + ((lane >> 4) << 1);      // f4-slot pair base
        const int xr = (rA & 7) << 2;
        f32x4 a0 = *(const f32x4*)&xs[b][(rA * 32 + ((s0 + 0) ^ xr)) * 4];
        f32x4 a1 = *(const f32x4*)&xs[b][(rA * 32 + ((s0 + 1) ^ xr)) * 4];
        bf16x8 ahi, alo;
        #pragma unroll
        for (int j = 0; j < 8; ++j) {
            float f = (j < 4) ? a0[j] : a1[j - 4];
            unsigned short h, l;
            split_bf16(f, h, l);
            ahi[j] = (short)h;
            alo[j] = (short)l;
        }
        #pragma unroll
        for (int n = 0; n < 4; ++n) {
            acc[hh][n] = __builtin_amdgcn_mfma_f32_16x16x32_bf16(ahi, B.v[0 + n], acc[hh][n], 0, 0, 0);
            acc[hh][n] = __builtin_amdgcn_mfma_f32_16x16x32_bf16(ahi, B.v[4 + n], acc[hh][n], 0, 0, 0);
            acc[hh][n] = __builtin_amdgcn_mfma_f32_16x16x32_bf16(alo, B.v[0 + n], acc[hh][n], 0, 0, 0);
        }
    };

    BSet BA, BB;

    // prologue: queue = [B(0):8, X0:2, X1:2, X2:2] = 14 -> wait(4) drains B0, X0
    load_b(0, BA);
    stage_x(0, 0);
    stage_x(1, 1);
    stage_x(2, 2);
    asm volatile("s_waitcnt vmcnt(4)" ::: "memory");
    __builtin_amdgcn_sched_barrier(0);
    __builtin_amdgcn_s_barrier();

    // steady state: issues alternate 10/2 per sub-iter; wait(12) = leave last
    // two sub-iters in flight -> drains B(c) (issued c-2) and X(c+1), keeps
    // X(c+2), X(c+3) (2 HBM chunks) + next B in flight. One barrier per chunk.
    #pragma unroll 1
    for (int c = 0; c < 28; c += 4) {
        load_b(c + 2, BB);
        stage_x(c + 3, (c + 3) & 3);
        asm volatile("s_waitcnt vmcnt(12)" ::: "memory");
        __builtin_amdgcn_sched_barrier(0);
        compute((c + 0) & 3, 0, BA);
        __builtin_amdgcn_s_barrier();

        stage_x(c + 4, (c + 4) & 3);
        asm volatile("s_waitcnt vmcnt(12)" ::: "memory");
        __builtin_amdgcn_sched_barrier(0);
        compute((c + 1) & 3, 1, BA);
        __builtin_amdgcn_s_barrier();

        load_b(c + 4, BA);
        stage_x(c + 5, (c + 5) & 3);
        asm volatile("s_waitcnt vmcnt(12)" ::: "memory");
        __builtin_amdgcn_sched_barrier(0);
        compute((c + 2) & 3, 0, BB);
        __builtin_amdgcn_s_barrier();

        stage_x(c + 6, (c + 6) & 3);
        asm volatile("s_waitcnt vmcnt(12)" ::: "memory");
        __builtin_amdgcn_sched_barrier(0);
        compute((c + 3) & 3, 1, BB);
        __builtin_amdgcn_s_barrier();
    }

    // tail: exact counts, no junk loads.
    // c=28: queue pre = [B28:8?drained.. = [B(28):8? no: [X29,X30 pending etc]
    load_b(30, BB);
    stage_x(31, 3);
    asm volatile("s_waitcnt vmcnt(12)" ::: "memory");   // drains B(28)=BA, X(29)
    __builtin_amdgcn_sched_barrier(0);
    compute(0, 0, BA);                                  // chunk 28
    __builtin_amdgcn_s_barrier();

    compute(1, 1, BA);                                  // chunk 29 (X29,BA already drained)
    __builtin_amdgcn_s_barrier();

    asm volatile("s_waitcnt vmcnt(2)" ::: "memory");    // drain X30, B30; leave X31
    __builtin_amdgcn_sched_barrier(0);
    compute(2, 0, BB);                                  // chunk 30
    __builtin_amdgcn_s_barrier();

    asm volatile("s_waitcnt vmcnt(0)" ::: "memory");
    __builtin_amdgcn_sched_barrier(0);
    compute(3, 1, BB);                                  // chunk 31
    __syncthreads();

    // 4-way k-quarter reduce into lg (deterministic serial order)
    // C/D layout: row_local = (lane>>4)*4 + j, col = n*16 + (lane&15)
    const int rb = (lane >> 4) << 2;
    const int cb = lane & 15;
    if (q == 0) {
        #pragma unroll
        for (int h = 0; h < 2; ++h)
            #pragma unroll
            for (int n = 0; n < 4; ++n)
                #pragma unroll
                for (int j = 0; j < 4; ++j)
                    lg[h * 16 + rb + j][n * 16 + cb] = acc[h][n][j];
    }
    __syncthreads();
    if (q == 1) {
        #pragma unroll
        for (int h = 0; h < 2; ++h)
            #pragma unroll
            for (int n = 0; n < 4; ++n)
                #pragma unroll
                for (int j = 0; j < 4; ++j)
                    lg[h * 16 + rb + j][n * 16 + cb] += acc[h][n][j];
    }
    __syncthreads();
    if (q == 2) {
        #pragma unroll
        for (int h = 0; h < 2; ++h)
            #pragma unroll
            for (int n = 0; n < 4; ++n)
                #pragma unroll
                for (int j = 0; j < 4; ++j)
                    lg[h * 16 + rb + j][n * 16 + cb] += acc[h][n][j];
    }
    __syncthreads();
    if (q == 3) {
        #pragma unroll
        for (int h = 0; h < 2; ++h)
            #pragma unroll
            for (int n = 0; n < 4; ++n)
                #pragma unroll
                for (int j = 0; j < 4; ++j)
                    lg[h * 16 + rb + j][n * 16 + cb] += acc[h][n][j];
    }
    __syncthreads();

    if (t < BM) {
        float m  = lg[t][0];
        int   mi = 0;
        #pragma unroll
        for (int e = 1; e < NE; ++e) {
            float v = lg[t][e];
            if (v > m) { m = v; mi = e; }
        }
        s_idx[t] = mi;
        out[row0 + t]         = (float)mi;
        out[BATCH + row0 + t] = m;
    }
    __syncthreads();

    // one-hot mask: 32 rows x 64 = 2048 floats; 8/thread, coalesced f32x4
    float* mask = out + 2 * (size_t)BATCH;
    int r  = t >> 3;
    int c0 = (t & 7) * 8;
    int mi = s_idx[r];
    #pragma unroll
    for (int i = 0; i < 2; ++i) {
        f32x4 v;
        #pragma unroll
        for (int j = 0; j < 4; ++j) v[j] = (c0 + i * 4 + j == mi) ? 1.0f : 0.0f;
        *(f32x4*)&mask[(size_t)(row0 + r) * NE + c0 + i * 4] = v;
    }
}

extern "C" void kernel_launch(void* const* d_in, const int* in_sizes, int n_in,
                              void* d_out, int out_size, void* d_ws, size_t ws_size,
                              hipStream_t stream) {
    const float* x = (const float*)d_in[0];
    const float* w = (const float*)d_in[1];
    float* out     = (float*)d_out;
    unsigned short* wf = (unsigned short*)d_ws;   // 512 KB

    wconv_kernel<<<dim3(512), dim3(256), 0, stream>>>(w, wf);
    gate_kernel<<<dim3(BATCH / BM), dim3(NT), 0, stream>>>(x, wf, out);
}